// Round 1
// baseline (1403.866 us; speedup 1.0000x reference)
//
#include <hip/hip_runtime.h>

#define BB 8
#define LL 2048
#define HH 8
#define DD 32
#define EE 256
#define NE 32
#define QB 8
#define NT 256
#define KPT (LL / NT)  // 8 keys per thread

// ---------------------------------------------------------------------------
// K1: per-head linear projection. One block per (n, l) row.
// out[n][h][l][e] = sum_d x[n][l][h*32+d] * W[e*32+d]   (y = x @ W^T)
// ---------------------------------------------------------------------------
__global__ __launch_bounds__(NT) void proj_kernel(const float* __restrict__ x,
                                                  const float* __restrict__ W,
                                                  float* __restrict__ out) {
  const int b = blockIdx.x;  // 0 .. B*L-1
  const int n = b / LL, l = b % LL;
  __shared__ float xs[EE];
  __shared__ float Ws[DD][DD + 1];  // padded: avoid bank conflicts
  const int t = threadIdx.x;
  xs[t] = x[(size_t)b * EE + t];
  for (int i = t; i < DD * DD; i += NT) Ws[i / DD][i % DD] = W[i];
  __syncthreads();
  const int h = t / DD, e = t % DD;
  float acc = 0.f;
#pragma unroll
  for (int d = 0; d < DD; ++d) acc = fmaf(xs[h * DD + d], Ws[e][d], acc);
  out[(((size_t)n * HH + h) * LL + l) * DD + e] = acc;
}

// ---------------------------------------------------------------------------
// K2: fused energy -> per-head softmax -> mean over heads -> top-32 -> output.
// One block per (n, block of QB=8 queries). 256 threads.
// Thread t owns keys k = j*256 + t (j = 0..7) for all 8 queries.
// ---------------------------------------------------------------------------
__global__ __launch_bounds__(NT) void attn_topk_kernel(const float* __restrict__ qp,
                                                       const float* __restrict__ kp,
                                                       int* __restrict__ out) {
  __shared__ float smean[QB][LL];    // 64 KB: mean-attention rows (gfx950 LDS = 160KB/CU)
  __shared__ float qs[QB][DD];       // current head's Q rows (broadcast reads)
  __shared__ float wredm[4][QB];     // cross-wave max scratch
  __shared__ float wreds[4][QB];     // cross-wave sum scratch
  __shared__ int topi[QB][NE];       // selected indices

  const int t = threadIdx.x;
  const int n = blockIdx.x / (LL / QB);
  const int q0 = (blockIdx.x % (LL / QB)) * QB;
  const int wid = t >> 6;

  {
    float* sm = &smean[0][0];
    for (int i = t; i < QB * LL; i += NT) sm[i] = 0.f;
  }

  float ev[QB][KPT];  // 64 energies, later reused as exp values

  for (int h = 0; h < HH; ++h) {
    __syncthreads();
    {  // stage Q rows for this head (256 threads == QB*DD elements)
      const int qi = t / DD, d = t % DD;
      qs[qi][d] = qp[(((size_t)n * HH + h) * LL + (q0 + qi)) * DD + d];
    }
    __syncthreads();

    const float* kb = kp + ((size_t)n * HH + h) * LL * DD;
#pragma unroll
    for (int j = 0; j < KPT; ++j) {
      const int k = j * NT + t;
      const float4* kr4 = (const float4*)(kb + (size_t)k * DD);
      float4 kr[DD / 4];
#pragma unroll
      for (int d4 = 0; d4 < DD / 4; ++d4) kr[d4] = kr4[d4];
#pragma unroll
      for (int q = 0; q < QB; ++q) {
        const float4* q4 = (const float4*)(&qs[q][0]);  // uniform addr: broadcast
        float acc = 0.f;
#pragma unroll
        for (int d4 = 0; d4 < DD / 4; ++d4) {
          float4 a = q4[d4];
          acc = fmaf(a.x, kr[d4].x, acc);
          acc = fmaf(a.y, kr[d4].y, acc);
          acc = fmaf(a.z, kr[d4].z, acc);
          acc = fmaf(a.w, kr[d4].w, acc);
        }
        ev[q][j] = acc;
      }
    }

    // --- row max over 2048 keys (block reduce) ---
    float m[QB];
#pragma unroll
    for (int q = 0; q < QB; ++q) {
      float v = ev[q][0];
#pragma unroll
      for (int j = 1; j < KPT; ++j) v = fmaxf(v, ev[q][j]);
      m[q] = v;
    }
#pragma unroll
    for (int off = 32; off >= 1; off >>= 1) {
#pragma unroll
      for (int q = 0; q < QB; ++q) m[q] = fmaxf(m[q], __shfl_xor(m[q], off));
    }
    if ((t & 63) == 0) {
#pragma unroll
      for (int q = 0; q < QB; ++q) wredm[wid][q] = m[q];
    }
    __syncthreads();
#pragma unroll
    for (int q = 0; q < QB; ++q)
      m[q] = fmaxf(fmaxf(wredm[0][q], wredm[1][q]), fmaxf(wredm[2][q], wredm[3][q]));

    // --- exp((e - m)/16) and Z (block reduce) ---
    float Zp[QB];
#pragma unroll
    for (int q = 0; q < QB; ++q) {
      float s = 0.f;
#pragma unroll
      for (int j = 0; j < KPT; ++j) {
        float x = __expf((ev[q][j] - m[q]) * 0.0625f);
        ev[q][j] = x;
        s += x;
      }
      Zp[q] = s;
    }
#pragma unroll
    for (int off = 32; off >= 1; off >>= 1) {
#pragma unroll
      for (int q = 0; q < QB; ++q) Zp[q] += __shfl_xor(Zp[q], off);
    }
    if ((t & 63) == 0) {
#pragma unroll
      for (int q = 0; q < QB; ++q) wreds[wid][q] = Zp[q];
    }
    __syncthreads();

    // --- accumulate softmax weights into mean rows (mean scale /8 is monotonic: skip) ---
#pragma unroll
    for (int q = 0; q < QB; ++q) {
      const float Z = wreds[0][q] + wreds[1][q] + wreds[2][q] + wreds[3][q];
      const float inv = 1.0f / Z;
#pragma unroll
      for (int j = 0; j < KPT; ++j) smean[q][j * NT + t] += ev[q][j] * inv;
    }
  }
  __syncthreads();

  // --- top-32 per query: 32-lane group g handles local query g ---
  const int g = t >> 5;
  const int lane = t & 31;
  float* row = &smean[g][0];

  for (int it = 0; it < NE; ++it) {
    float bv = -2.f;
    int bi = 1 << 30;
    // scan ascending index; strict '>' keeps lowest index on ties (top_k semantics)
    for (int mm = 0; mm < LL / 128; ++mm) {
      const int base = mm * 128 + lane * 4;
      float4 v = *(const float4*)(&row[base]);
      if (v.x > bv) { bv = v.x; bi = base; }
      if (v.y > bv) { bv = v.y; bi = base + 1; }
      if (v.z > bv) { bv = v.z; bi = base + 2; }
      if (v.w > bv) { bv = v.w; bi = base + 3; }
    }
#pragma unroll
    for (int off = 16; off >= 1; off >>= 1) {
      float ov = __shfl_xor(bv, off, 32);
      int oi = __shfl_xor(bi, off, 32);
      if (ov > bv || (ov == bv && oi < bi)) { bv = ov; bi = oi; }
    }
    if (((bi >> 2) & 31) == lane) row[bi] = -1.f;  // owner clears winner
    if (lane == 0) topi[g][it] = bi;
  }
  __syncthreads();

  // --- sort 32 distinct indices ascending via rank, write output ---
  const int myv = topi[g][lane];
  int rank = 0;
#pragma unroll
  for (int j = 0; j < NE; ++j) rank += (topi[g][j] < myv) ? 1 : 0;

  const int qg = q0 + g;
  int* o0 = out + (size_t)n * 2 * LL * NE + (size_t)qg * NE;
  int* o1 = o0 + (size_t)LL * NE;
  o0[lane] = qg;    // row 0: source node
  o1[rank] = myv;   // row 1: sorted neighbor indices
}

// ---------------------------------------------------------------------------
extern "C" void kernel_launch(void* const* d_in, const int* in_sizes, int n_in,
                              void* d_out, int out_size, void* d_ws, size_t ws_size,
                              hipStream_t stream) {
  const float* keys = (const float*)d_in[0];
  const float* query = (const float*)d_in[1];
  const float* Wk = (const float*)d_in[2];
  const float* Wq = (const float*)d_in[3];
  int* out = (int*)d_out;

  float* qp = (float*)d_ws;                       // [B][H][L][32] f32, 16.8 MB
  float* kp = qp + (size_t)BB * HH * LL * DD;     // [B][H][L][32] f32, 16.8 MB

  proj_kernel<<<BB * LL, NT, 0, stream>>>(query, Wq, qp);
  proj_kernel<<<BB * LL, NT, 0, stream>>>(keys, Wk, kp);
  attn_topk_kernel<<<BB * (LL / QB), NT, 0, stream>>>(qp, kp, out);
}

// Round 2
// 517.716 us; speedup vs baseline: 2.7117x; 2.7117x over previous
//
#include <hip/hip_runtime.h>
#include <hip/hip_bf16.h>

#define NB 8
#define LSEQ 2048
#define HH 8
#define DD 32
#define EE 256
#define NE 32
#define QT 16      // queries per block
#define NWAVE 16
#define NTH 1024
#define KW 128     // keys per wave
#define NTILE 8    // KW / 16
#define SMS 2052   // smean row stride in words (16B-aligned rows, 2-way-max bank alias)

typedef __attribute__((ext_vector_type(8))) short short8;
typedef __attribute__((ext_vector_type(4))) float f32x4;

// ---------------------------------------------------------------------------
// K1: per-head projection -> 3-way bf16 split (hi/mid/lo = 24 mantissa bits).
// out[n][h][l][e] = sum_d x[n][l][h*32+d] * W[e*32+d]
// ---------------------------------------------------------------------------
__global__ __launch_bounds__(256) void proj_kernel(const float* __restrict__ x,
                                                   const float* __restrict__ W,
                                                   __hip_bfloat16* __restrict__ o1,
                                                   __hip_bfloat16* __restrict__ o2,
                                                   __hip_bfloat16* __restrict__ o3) {
  const int b = blockIdx.x;  // n*L + l
  const int n = b / LSEQ, l = b % LSEQ;
  __shared__ float xs[EE];
  __shared__ float Ws[DD][DD + 1];
  const int t = threadIdx.x;
  xs[t] = x[(size_t)b * EE + t];
  for (int i = t; i < DD * DD; i += 256) Ws[i / DD][i % DD] = W[i];
  __syncthreads();
  const int h = t / DD, e = t % DD;
  float acc = 0.f;
#pragma unroll
  for (int d = 0; d < DD; ++d) acc = fmaf(xs[h * DD + d], Ws[e][d], acc);
  const size_t oi = (((size_t)n * HH + h) * LSEQ + l) * DD + e;
  __hip_bfloat16 p1 = __float2bfloat16(acc);
  float r1 = acc - __bfloat162float(p1);
  __hip_bfloat16 p2 = __float2bfloat16(r1);
  float r2 = r1 - __bfloat162float(p2);
  __hip_bfloat16 p3 = __float2bfloat16(r2);
  o1[oi] = p1;
  o2[oi] = p2;
  o3[oi] = p3;
}

// ---------------------------------------------------------------------------
// K2: MFMA energy -> per-head softmax -> mean accumulate (LDS) -> top-32.
// One block = (n, tile of 16 queries). 16 waves; wave w owns keys [w*128,(w+1)*128).
// Energies held in MFMA C fragments (8 x f32x4 per lane).
// ---------------------------------------------------------------------------
__global__ __launch_bounds__(NTH) void attn_topk_kernel(
    const __hip_bfloat16* __restrict__ q1, const __hip_bfloat16* __restrict__ q2,
    const __hip_bfloat16* __restrict__ q3, const __hip_bfloat16* __restrict__ k1,
    const __hip_bfloat16* __restrict__ k2, const __hip_bfloat16* __restrict__ k3,
    int* __restrict__ out) {
  __shared__ float smean[QT * SMS];  // 131 KB mean-attn rows
  __shared__ float wredT[QT][16];    // cross-wave max partials
  __shared__ float wredS[QT][16];    // cross-wave sum partials

  const int t = threadIdx.x;
  const int w = t >> 6, l = t & 63;
  const int g = l >> 4, c = l & 15;  // 16-lane group / lane-in-group
  const int n = blockIdx.x & 7;      // XCD-aligned batch assignment
  const int q0 = (blockIdx.x >> 3) * QT;

  for (int i = t; i < QT * SMS; i += NTH) smean[i] = 0.f;
  __syncthreads();

  for (int h = 0; h < HH; ++h) {
    const size_t hb = ((size_t)n * HH + h) * LSEQ;
    // A fragment (Q): row = c, d-range = g*8..g*8+7
    const size_t qoff = (hb + q0 + c) * DD + (size_t)g * 8;
    const short8 aH = *(const short8*)(q1 + qoff);
    const short8 aM = *(const short8*)(q2 + qoff);
    const short8 aL = *(const short8*)(q3 + qoff);

    f32x4 acc[NTILE];
#pragma unroll
    for (int t2 = 0; t2 < NTILE; ++t2) {
      // B fragment (K): col = c, d-range = g*8..g*8+7
      const size_t koff = (hb + (size_t)w * KW + t2 * 16 + c) * DD + (size_t)g * 8;
      const short8 bH = *(const short8*)(k1 + koff);
      const short8 bM = *(const short8*)(k2 + koff);
      const short8 bL = *(const short8*)(k3 + koff);
      f32x4 a = {0.f, 0.f, 0.f, 0.f};
      a = __builtin_amdgcn_mfma_f32_16x16x32_bf16(aH, bH, a, 0, 0, 0);
      a = __builtin_amdgcn_mfma_f32_16x16x32_bf16(aH, bM, a, 0, 0, 0);
      a = __builtin_amdgcn_mfma_f32_16x16x32_bf16(aM, bH, a, 0, 0, 0);
      a = __builtin_amdgcn_mfma_f32_16x16x32_bf16(aH, bL, a, 0, 0, 0);
      a = __builtin_amdgcn_mfma_f32_16x16x32_bf16(aL, bH, a, 0, 0, 0);
      a = __builtin_amdgcn_mfma_f32_16x16x32_bf16(aM, bM, a, 0, 0, 0);
      acc[t2] = a;
    }

    // --- row max: lane-local over 8 tiles, then 16-lane group, then cross-wave ---
    float m[4];
#pragma unroll
    for (int r = 0; r < 4; ++r) {
      float v = acc[0][r];
#pragma unroll
      for (int t2 = 1; t2 < NTILE; ++t2) v = fmaxf(v, acc[t2][r]);
      m[r] = v;
    }
#pragma unroll
    for (int msk = 1; msk <= 8; msk <<= 1)
#pragma unroll
      for (int r = 0; r < 4; ++r) m[r] = fmaxf(m[r], __shfl_xor(m[r], msk));
    if (c == 0) {
#pragma unroll
      for (int r = 0; r < 4; ++r) wredT[g * 4 + r][w] = m[r];
    }
    __syncthreads();
    // lane c reads wave-c partial, group-shuffle combines all 16 waves
    float fm[4];
#pragma unroll
    for (int r = 0; r < 4; ++r) fm[r] = wredT[g * 4 + r][c];
#pragma unroll
    for (int msk = 1; msk <= 8; msk <<= 1)
#pragma unroll
      for (int r = 0; r < 4; ++r) fm[r] = fmaxf(fm[r], __shfl_xor(fm[r], msk));

    // --- exp((e-m)/16) in place + partial Z ---
    float Zl[4] = {0.f, 0.f, 0.f, 0.f};
#pragma unroll
    for (int t2 = 0; t2 < NTILE; ++t2) {
#pragma unroll
      for (int r = 0; r < 4; ++r) {
        float e = __expf((acc[t2][r] - fm[r]) * 0.0625f);
        acc[t2][r] = e;
        Zl[r] += e;
      }
    }
#pragma unroll
    for (int msk = 1; msk <= 8; msk <<= 1)
#pragma unroll
      for (int r = 0; r < 4; ++r) Zl[r] += __shfl_xor(Zl[r], msk);
    if (c == 0) {
#pragma unroll
      for (int r = 0; r < 4; ++r) wredS[g * 4 + r][w] = Zl[r];
    }
    __syncthreads();
    float inv[4];
#pragma unroll
    for (int r = 0; r < 4; ++r) {
      float z = wredS[g * 4 + r][c];
#pragma unroll
      for (int msk = 1; msk <= 8; msk <<= 1) z += __shfl_xor(z, msk);
      inv[r] = 1.0f / z;
    }
    // --- accumulate softmax weights into mean rows (mean /8 is monotonic: skip) ---
#pragma unroll
    for (int t2 = 0; t2 < NTILE; ++t2) {
#pragma unroll
      for (int r = 0; r < 4; ++r) {
        smean[(g * 4 + r) * SMS + w * KW + t2 * 16 + c] += acc[t2][r] * inv[r];
      }
    }
  }
  __syncthreads();

  // --- top-32: wave w owns query q0+w; 2048 values -> 32 regs/lane (k = j*64+l) ---
  float* row = &smean[w * SMS];
  float vals[32];
  float v1 = -1e30f, v2 = -1e30f;
  int i1 = 1 << 30, i2 = 1 << 30;
#pragma unroll
  for (int j = 0; j < 32; ++j) {
    float v = row[j * 64 + l];
    vals[j] = v;
    const int k = j * 64 + l;
    if (v > v1) { v2 = v1; i2 = i1; v1 = v; i1 = k; }
    else if (v > v2) { v2 = v; i2 = k; }
  }
  unsigned rem = 0u;
  int selk = 0;
#pragma unroll 1
  for (int it = 0; it < NE; ++it) {
    // wave argmax over cached lane-maxima (tie -> lowest index)
    float bv = v1;
    int bk = i1;
#pragma unroll
    for (int off = 32; off >= 1; off >>= 1) {
      float ov = __shfl_xor(bv, off);
      int ok = __shfl_xor(bk, off);
      if (ov > bv || (ov == bv && ok < bk)) { bv = ov; bk = ok; }
    }
    if (l == it) selk = bk;
    if (i1 == bk) {  // this lane supplied the winner
      rem |= 1u << (bk >> 6);
      if (i2 != (1 << 30)) {  // promote cached second
        v1 = v2; i1 = i2;
        v2 = -1e30f; i2 = 1 << 30;
      } else {  // rare: rebuild top-2 from masked registers
        v1 = -1e30f; i1 = 1 << 30;
        v2 = -1e30f; i2 = 1 << 30;
#pragma unroll
        for (int j = 0; j < 32; ++j) {
          float v = ((rem >> j) & 1u) ? -1e30f : vals[j];
          const int k = j * 64 + l;
          if (v > v1) { v2 = v1; i2 = i1; v1 = v; i1 = k; }
          else if (v > v2) { v2 = v; i2 = k; }
        }
      }
    }
  }

  // --- rank-sort the 32 winners by index, write output ---
  int rank = 0;
#pragma unroll
  for (int j = 0; j < NE; ++j) {
    int o = __shfl(selk, j);
    rank += (o < selk) ? 1 : 0;
  }
  const int qg = q0 + w;
  if (l < NE) {
    int* o0 = out + (size_t)n * 2 * LSEQ * NE + (size_t)qg * NE;
    int* o1p = o0 + (size_t)LSEQ * NE;
    o0[l] = qg;
    o1p[rank] = selk;
  }
}

// ---------------------------------------------------------------------------
extern "C" void kernel_launch(void* const* d_in, const int* in_sizes, int n_in,
                              void* d_out, int out_size, void* d_ws, size_t ws_size,
                              hipStream_t stream) {
  const float* keys = (const float*)d_in[0];
  const float* query = (const float*)d_in[1];
  const float* Wk = (const float*)d_in[2];
  const float* Wq = (const float*)d_in[3];
  int* out = (int*)d_out;

  const size_t SPLIT = (size_t)NB * HH * LSEQ * DD;  // 4,194,304 elems
  __hip_bfloat16* qs1 = (__hip_bfloat16*)d_ws;
  __hip_bfloat16* qs2 = qs1 + SPLIT;
  __hip_bfloat16* qs3 = qs2 + SPLIT;
  __hip_bfloat16* ks1 = qs3 + SPLIT;
  __hip_bfloat16* ks2 = ks1 + SPLIT;
  __hip_bfloat16* ks3 = ks2 + SPLIT;

  proj_kernel<<<NB * LSEQ, 256, 0, stream>>>(query, Wq, qs1, qs2, qs3);
  proj_kernel<<<NB * LSEQ, 256, 0, stream>>>(keys, Wk, ks1, ks2, ks3);
  attn_topk_kernel<<<NB * (LSEQ / QT), NTH, 0, stream>>>(qs1, qs2, qs3, ks1, ks2, ks3, out);
}